// Round 13
// baseline (335.594 us; speedup 1.0000x reference)
//
#include <hip/hip_runtime.h>

// EdgeFeatGAE: 2-layer GCN (R=4 relations share x, W1, W2), out = sum over
// embed dim -> [R, N].
// Algebra: layer2 collapses to scalar per node (wrow[j] = sum_k W2[j][k]);
// H0 = x@W1 is relation-independent; q[i] = dinv_i * g_i makes layer2 a pure
// scalar gather: out_i = dinv_i*(sum_src q[src] + q[i]) + sum(b2).
// R5-R9: radix-partition + per-bucket counting sort + packed gathers:
// 1738->436us. R11: 16 lanes/node. R12: pre-scaled Hsc=dinv*H0. R13:
// fixedsrc first-16 prefix. R14: register-batched scat2. 406->371us.
// R15: gemm_h0 wave-uniform W1 s_load + LDS-staged x. 371->335us.
// R18 FAILED: per-edge direct scatter -> 64B partial-line writebacks.
// R19: prefix/overflow split (only ~9% of records materialized). ->306.7us.
// R20: meta int4 pack. 306.7us, k_l1 68.0.
// R21 FAILED (315.7): gathering raw H0h didn't shrink the set - each
// relation's Hsc gathers already touch only their own 6.4MB slice; R21
// just re-added the dinv gather (R12's lesson, +14us both directions).
// Diagnosis: 6.4MB per-relation gather set > 4MB per-XCD L2 -> random 64B
// row gathers miss L2 -> 207MB fabric fetch @ ~3TB/s = k_l1's wall.
// R22: j-SPLIT the pre-scaled rows: HscA = j0..15 (32B), HscB = j16..31.
// k_l1 runs two passes (A -> partial dot qp; B -> q = di*(pA+pB); exact:
// p = sum_j relu(h1_j)*wrow_j separates over j). Per-pass gather set =
// 3.2MB < 4MB L2 -> gathers become L2 hits. Same 2-hop chain, same
// records/wave-gather (4 lanes x 8B), pre-scaled (no dinv gather).

constexpr int N    = 100000;
constexpr int E    = 1600000;
constexpr int R    = 4;
constexpr int FEAT = 128;
constexpr int HID  = 32;
constexpr int EMB  = 16;
constexpr int M    = R * N;
constexpr int BS   = 256;
constexpr int SH    = 9;                          // bucket = node >> 9
constexpr int BSPAN = 1 << SH;                    // 512 nodes per bucket
constexpr int NBUCK = (N + BSPAN - 1) / BSPAN;    // 196 buckets per relation
constexpr int CH    = 4096;                       // edges per block chunk
constexpr int EPT   = CH / BS;                    // 16 edges per thread
constexpr int NBKr  = (E + CH - 1) / CH;          // 391 blocks per relation
constexpr int RB    = R * NBUCK;                  // 784 buckets total
constexpr int CAP   = 8960;                       // bucket capacity (8.5 sigma)
constexpr int SPT   = (CAP + BSPAN - 1) / BSPAN;  // 18 records per sort thread
constexpr int OCAP  = 1536;                       // overflow cap/bucket (~13 sigma)
constexpr int FIX   = 16;                         // fixed adjacency prefix
constexpr int GNB   = 64;                         // nodes per gemm block (R15)
constexpr int XPITCH = 132;                       // LDS row pitch floats (R15)

typedef _Float16 half8 __attribute__((ext_vector_type(8)));   // 16B chunk
typedef _Float16 half4 __attribute__((ext_vector_type(4)));   // 8B chunk
typedef _Float16 half2v __attribute__((ext_vector_type(2)));  // packed pair

// ---------------- H0 = x @ W1  [N,32] -> fp16 ----------------
// R15: lane=node, wave=j-octet (uniform -> W1 via s_load). x staged in LDS
// with XOR-swizzled float4 columns -> conflict-free ds_read_b128.
__global__ __launch_bounds__(BS)
void k_gemm_h0(const float* __restrict__ x, const float* __restrict__ W1,
               _Float16* __restrict__ H0h) {
    __shared__ float xs[GNB * XPITCH];            // 33 KB
    int base = blockIdx.x * GNB;
    int tid  = threadIdx.x;
#pragma unroll
    for (int u = 0; u < 8; ++u) {
        int f = tid + u * BS;          // float4 index in [64][32]
        int n = f >> 5;                // node in block
        int c = f & 31;                // logical float4 column
        if (base + n < N) {
            float4 v = ((const float4*)(x + (size_t)(base + n) * FEAT))[c];
            int p = c ^ ((n & 7) << 2);            // swizzled column
            *(float4*)&xs[n * XPITCH + p * 4] = v;
        }
    }
    __syncthreads();
    int oct = __builtin_amdgcn_readfirstlane(tid >> 6);   // wave-uniform octet
    int l   = tid & 63;                // node owned by this lane
    int i   = base + l;
    const float* wp = W1 + oct * 8;    // uniform base: W1[k][oct*8+j]
    float acc[8];
#pragma unroll
    for (int kk = 0; kk < 8; ++kk) acc[kk] = 0.f;
#pragma unroll 4
    for (int c = 0; c < 32; ++c) {
        int p = c ^ ((l & 7) << 2);
        float4 xv = *(const float4*)&xs[l * XPITCH + p * 4];
        float xk[4] = {xv.x, xv.y, xv.z, xv.w};
#pragma unroll
        for (int dk = 0; dk < 4; ++dk) {
            const float* wr = wp + (c * 4 + dk) * HID;    // uniform -> s_load
#pragma unroll
            for (int j = 0; j < 8; ++j)
                acc[j] = fmaf(xk[dk], wr[j], acc[j]);
        }
    }
    half8 hv;
#pragma unroll
    for (int kk = 0; kk < 8; ++kk) hv[kk] = (_Float16)acc[kk];
    if (i < N) ((half8*)H0h)[i * 4 + oct] = hv;   // 16B store
}

// ---- wrow[j] = sum_k W2[j][k]; wrowbuf[32] = sum(b2); HscA/B zero rows ----
__global__ void k_wrow(const float* __restrict__ W2, const float* __restrict__ b2,
                       float* __restrict__ wrowbuf, _Float16* __restrict__ HscA,
                       _Float16* __restrict__ HscB) {
    int j = threadIdx.x;
    if (j < HID) {
        float s = 0.f;
#pragma unroll
        for (int k = 0; k < EMB; ++k) s += W2[j * EMB + k];
        wrowbuf[j] = s;
    } else if (j == HID) {
        float s = 0.f;
#pragma unroll
        for (int k = 0; k < EMB; ++k) s += b2[k];
        wrowbuf[HID] = s;
    } else if (j >= 34 && j < 42) {
        ((unsigned*)(HscA + (size_t)M * 16))[j - 34] = 0u;   // zero pad row
    } else if (j >= 42 && j < 50) {
        ((unsigned*)(HscB + (size_t)M * 16))[j - 42] = 0u;   // zero pad row
    }
}

// ---------------- partition: register-batched loads (R14) ------------------
__global__ void k_scat2(const int* __restrict__ eis, int* __restrict__ gcur,
                        int* __restrict__ binned) {
    __shared__ int hist[NBUCK], lstart[NBUCK], cursor[NBUCK], gbase[NBUCK];
    __shared__ int wpart[BS / 64];
    __shared__ int shuf[CH];              // 16 KB
    __shared__ unsigned char bkt[CH];     // 4 KB
    int r = blockIdx.x / NBKr, k = blockIdx.x - r * NBKr;
    const int* srcp = eis + (size_t)r * 2 * E;
    const int* dstp = srcp + E;
    int e0 = k * CH, n = min(CH, E - e0);
    int tid = threadIdx.x;

    // R14: batch all global loads up-front into registers.
    int dreg[EPT], sreg[EPT];
    if (n == CH) {
#pragma unroll
        for (int u = 0; u < EPT; ++u) {
            dreg[u] = dstp[e0 + tid + u * BS];
            sreg[u] = srcp[e0 + tid + u * BS];
        }
    } else {
#pragma unroll
        for (int u = 0; u < EPT; ++u) {
            int i = tid + u * BS;
            dreg[u] = (i < n) ? dstp[e0 + i] : -1;   // sentinel
            sreg[u] = (i < n) ? srcp[e0 + i] : 0;
        }
    }
    for (int b = tid; b < NBUCK; b += BS) hist[b] = 0;
    __syncthreads();
#pragma unroll
    for (int u = 0; u < EPT; ++u)
        if (dreg[u] >= 0) atomicAdd(&hist[dreg[u] >> SH], 1);
    __syncthreads();
    // exclusive prefix over NBUCK entries: wave shfl scan (R12)
    int v = (tid < NBUCK) ? hist[tid] : 0;
    int lanei = tid & 63;
    int s = v;
#pragma unroll
    for (int d = 1; d < 64; d <<= 1) {
        int xup = __shfl_up(s, d, 64);
        s += (lanei >= d) ? xup : 0;
    }
    if (lanei == 63) wpart[tid >> 6] = s;
    __syncthreads();
    int offw = 0;
#pragma unroll
    for (int ww = 0; ww < BS / 64; ++ww)
        offw += (ww < (tid >> 6)) ? wpart[ww] : 0;
    int ex = offw + s - v;                // exclusive prefix
    if (tid < NBUCK) {
        lstart[tid] = ex;
        cursor[tid] = ex;
        gbase[tid] = atomicAdd(&gcur[r * NBUCK + tid], v);
    }
    __syncthreads();
    // local scatter into LDS (bucket-ordered), from registers
#pragma unroll
    for (int u = 0; u < EPT; ++u) {
        int d = dreg[u];
        if (d >= 0) {
            int b = d >> SH;
            int pos = atomicAdd(&cursor[b], 1);
            shuf[pos] = ((d & (BSPAN - 1)) << 17) | sreg[u];   // src < 2^17
            bkt[pos]  = (unsigned char)b;
        }
    }
    __syncthreads();
    // coalesced emission into CAP-strided bucket segments (R20 unroll)
    if (n == CH) {
#pragma unroll
        for (int u = 0; u < EPT; ++u) {
            int i = tid + u * BS;
            int b = bkt[i];
            int pos = gbase[b] + (i - lstart[b]);
            if (pos < CAP)
                binned[(size_t)(r * NBUCK + b) * CAP + pos] = shuf[i];
        }
    } else {
        for (int i = tid; i < n; i += BS) {
            int b = bkt[i];
            int pos = gbase[b] + (i - lstart[b]);
            if (pos < CAP)
                binned[(size_t)(r * NBUCK + b) * CAP + pos] = shuf[i];
        }
    }
}

// ------ per-bucket prefix/overflow split (R19) + meta + split Hsc ----------
// Counts per node, writes fixed-16 prefix via fix_lds (coalesced), the ~9%
// overflow compactly into the TAIL of this bucket's binned segment, and the
// j-split pre-scaled rows HscA (j0..15) / HscB (j16..31).
__global__ __launch_bounds__(BSPAN)
void k_sort3(const int* __restrict__ gcur, int* __restrict__ binned,
             int4* __restrict__ meta, const half8* __restrict__ H0h,
             half8* __restrict__ HscA, half8* __restrict__ HscB,
             int* __restrict__ fixedsrc) {
    __shared__ int fix_lds[FIX * BSPAN];            // 32 KB, transposed [k][node]
    __shared__ int hist[BSPAN], cur[BSPAN], oexs[BSPAN];  // 6 KB
    __shared__ int wpart[BSPAN / 64];
    int gb = blockIdx.x;
    int r = gb / NBUCK, b = gb - r * NBUCK;
    int n = min(gcur[gb], CAP);
    int base = gb * CAP;
    int ovb  = base + (CAP - OCAP);       // overflow region: tail of own segment
    int tid = threadIdx.x;                // 0..511
    int node = (b << SH) + tid;
    int ri = r * N + node;
    // R20: H0h self-row loads have static addresses - issue at entry.
    int nodec = min(node, N - 1);
    half8 h0r[4];
#pragma unroll
    for (int cc = 0; cc < 4; ++cc) h0r[cc] = H0h[(size_t)nodec * 4 + cc];
    // register-resident records (R16): all loads in flight, no LDS staging
    int rg[SPT];
#pragma unroll
    for (int u = 0; u < SPT; ++u) {
        int i = tid + u * BSPAN;
        rg[u] = (i < n) ? binned[base + i] : -1;    // values >= 0; -1 sentinel
    }
    hist[tid] = 0;
    cur[tid] = 0;
    __syncthreads();
#pragma unroll
    for (int u = 0; u < SPT; ++u)
        if (rg[u] >= 0) atomicAdd(&hist[((unsigned)rg[u]) >> 17], 1);
    __syncthreads();
    int v = hist[tid];
    int ov = max(v - FIX, 0);             // this node's overflow count
    // wave shfl scan + cross-wave pass over overflow counts
    int lanei = tid & 63;
    int s = ov;
#pragma unroll
    for (int d = 1; d < 64; d <<= 1) {
        int xup = __shfl_up(s, d, 64);
        s += (lanei >= d) ? xup : 0;
    }
    if (lanei == 63) wpart[tid >> 6] = s;
    __syncthreads();
    int offw = 0;
#pragma unroll
    for (int ww = 0; ww < BSPAN / 64; ++ww)
        offw += (ww < (tid >> 6)) ? wpart[ww] : 0;
    int oex = offw + s - ov;              // exclusive prefix of overflow
    oexs[tid] = oex;
    float di = rsqrtf((float)v + 1.0f);
    if (node < N) {
        int4 mw;
        mw.x = min(v, FIX + max(OCAP - oex, 0));   // clamped cnt (13-sigma no-op)
        mw.y = ovb + oex;                          // overflow base
        mw.z = __float_as_int(di);                 // dinv bits
        mw.w = 0;
        meta[ri] = mw;                             // one coalesced 16B store
    }
    __syncthreads();
    // split scatter: k<FIX -> fix_lds (coalesced out later); else -> compact
    // overflow tail. Arrival order arbitrary = correct (commutative sum,
    // validated R18). Reads of rg are register-resident -> tail aliasing ok.
#pragma unroll
    for (int u = 0; u < SPT; ++u) {
        int rc = rg[u];
        if (rc >= 0) {
            int nd = ((unsigned)rc) >> 17;
            int k = atomicAdd(&cur[nd], 1);
            int val = rc & 0x1FFFF;
            if (k < FIX) {
                fix_lds[k * BSPAN + nd] = val;
            } else {
                int p = oexs[nd] + k - FIX;
                if (p < OCAP) binned[ovb + p] = val;
            }
        }
    }
    __syncthreads();
    // fused epilogue: fixedsrc prefix + HscA/HscB = dinv*H0, all coalesced
    if (node < N) {
        int nn = min(v, FIX);
#pragma unroll
        for (int cc = 0; cc < 4; ++cc) {
            int4 w;
            w.x = (cc * 4 + 0 < nn) ? fix_lds[(cc * 4 + 0) * BSPAN + tid] : 0;
            w.y = (cc * 4 + 1 < nn) ? fix_lds[(cc * 4 + 1) * BSPAN + tid] : 0;
            w.z = (cc * 4 + 2 < nn) ? fix_lds[(cc * 4 + 2) * BSPAN + tid] : 0;
            w.w = (cc * 4 + 3 < nn) ? fix_lds[(cc * 4 + 3) * BSPAN + tid] : 0;
            ((int4*)(fixedsrc + (size_t)ri * FIX))[cc] = w;   // coalesced 64B
        }
#pragma unroll
        for (int cc = 0; cc < 4; ++cc) {
            half8 h = h0r[cc];
            half8 o;
#pragma unroll
            for (int kk = 0; kk < 8; ++kk) o[kk] = (_Float16)(di * (float)h[kk]);
            if (cc < 2) HscA[(size_t)ri * 2 + cc] = o;        // j 0..15
            else        HscB[(size_t)ri * 2 + (cc - 2)] = o;  // j 16..31
        }
    }
}

// -------- layer 1, pass P: 16 lanes/node, 4 lanes/record, 8B chunks --------
// R22: per-pass gather set = HscP per-relation slice = 3.2MB < 4MB L2.
// PASS 0 writes partial dot qp[ri]; PASS 1 finalizes q = di*(pA+pB).
template<int PASS>
__global__ void k_l1(const int4* __restrict__ meta, const int* __restrict__ ssrc,
                     const int* __restrict__ fixedsrc, const half4* __restrict__ Hp,
                     const float* __restrict__ b1, const float* __restrict__ wrowbuf,
                     float* __restrict__ qp, float* __restrict__ q) {
    int t = blockIdx.x * blockDim.x + threadIdx.x;
    int ri = t >> 4;
    if (ri >= M) return;
    int lane = t & 15;
    int c   = lane & 3;        // 8B chunk of the 32B row
    int sub = lane >> 2;       // record slot 0..3
    int i = ri % N;
    int rbase = ri - i;
    int fs = fixedsrc[(size_t)ri * FIX + lane];    // STATIC addr: issues now
    half4 hs = Hp[(size_t)ri * 4 + c];             // STATIC addr: self chunk
    float pprev = (PASS == 1) ? qp[ri] : 0.f;      // STATIC addr
    int4 mo = meta[ri];                            // one dwordx4: cnt|ovoff|dinv
    int n = mo.x;
    int base = mo.y - FIX;                         // virtual base for k0>=16
    float di = __int_as_float(mo.z);
    half2v acc[2];
    half2v zz = {(_Float16)0.f, (_Float16)0.f};
    acc[0] = zz; acc[1] = zz;

    auto procwin = [&](int sbv, int m) {
        for (int bq = 0; bq < 4 && bq * 4 < m; ++bq) {
            int slot = bq * 4 + sub;
            int sj = __shfl(sbv, slot, 16);
            int idx = (slot < m) ? (rbase + sj) : M;   // zero row for pad slots
            half4 h = Hp[(size_t)idx * 4 + c];         // 8B/lane, L2-hot set
            half2v h0 = {h[0], h[1]};
            half2v h1 = {h[2], h[3]};
            acc[0] = acc[0] + h0;                      // v_pk_add_f16
            acc[1] = acc[1] + h1;
        }
    };

    // prefetch window 1 (first overflow window) before processing window 0
    int sb = (16 + lane < n) ? ssrc[base + 16 + lane] : 0;
    procwin(fs, n);                                 // window 0 (from fixed)
    for (int k0 = 16; k0 < n; k0 += 16) {
        int sbn = (k0 + 16 + lane < n) ? ssrc[base + k0 + 16 + lane] : 0;
        procwin(sb, n - k0);
        sb = sbn;
    }
    // packed reduction over record slots (lanes c, c+4, c+8, c+12 same chunk)
#pragma unroll
    for (int o = 4; o <= 8; o <<= 1) {
#pragma unroll
        for (int kk = 0; kk < 2; ++kk) {
            int av = __builtin_bit_cast(int, acc[kk]);
            av = __shfl_xor(av, o, 16);
            acc[kk] = acc[kk] + __builtin_bit_cast(half2v, av);  // v_pk_add_f16
        }
    }
    // self term
    {
        half2v h0 = {hs[0], hs[1]};
        half2v h1 = {hs[2], hs[3]};
        acc[0] = acc[0] + h0;
        acc[1] = acc[1] + h1;
    }
    // epilogue: h1 = relu(di*acc + b1[j]); p = h1 . wrow[j], j = P*16+c*4+kk
    float p = 0.f;
#pragma unroll
    for (int kk = 0; kk < 4; ++kk) {
        float av = (float)acc[kk >> 1][kk & 1];
        int j = PASS * 16 + c * 4 + kk;
        float h1 = fmaf(di, av, b1[j]);
        h1 = fmaxf(h1, 0.f);
        p = fmaf(h1, wrowbuf[j], p);
    }
    p += __shfl_xor(p, 1, 16);
    p += __shfl_xor(p, 2, 16);
    if (lane == 0) {
        if (PASS == 0) qp[ri] = p;
        else           q[ri] = di * (p + pprev);   // q = dinv * g
    }
}

// ---------------- layer 2: per-lane scalar gathers of q + finalize ----------
__global__ void k_l2(const int4* __restrict__ meta, const int* __restrict__ ssrc,
                     const int* __restrict__ fixedsrc, const float* __restrict__ q,
                     const float* __restrict__ wrowbuf, float* __restrict__ out) {
    int t = blockIdx.x * blockDim.x + threadIdx.x;
    int ri = t >> 3;
    if (ri >= M) return;
    int lane = t & 7;
    int i = ri % N;
    int rbase = ri - i;
    int f0 = fixedsrc[(size_t)ri * FIX + lane];        // static addr
    int f1 = fixedsrc[(size_t)ri * FIX + 8 + lane];    // static addr
    int4 mo = meta[ri];                                // cnt | ovoff | dinv
    int n = mo.x;
    int base = mo.y - FIX;
    float val = 0.f;
    if (lane < n)     val += q[rbase + f0];
    if (8 + lane < n) val += q[rbase + f1];
    for (int idx = 16 + lane; idx < n; idx += 8) {
        int s = ssrc[base + idx];               // coalesced (overflow list)
        val += q[rbase + s];                    // 4B gather, 1.6MB L2-resident
    }
#pragma unroll
    for (int o = 4; o > 0; o >>= 1) val += __shfl_xor(val, o, 8);
    if (lane == 0)
        out[ri] = __int_as_float(mo.z) * (val + q[ri]) + wrowbuf[HID];
}

extern "C" void kernel_launch(void* const* d_in, const int* in_sizes, int n_in,
                              void* d_out, int out_size, void* d_ws, size_t ws_size,
                              hipStream_t stream) {
    const float* x  = (const float*)d_in[0];
    const int*  eis = (const int*)d_in[1];
    const float* W1 = (const float*)d_in[2];
    const float* b1 = (const float*)d_in[3];
    const float* W2 = (const float*)d_in[4];
    const float* b2 = (const float*)d_in[5];
    float* out = (float*)d_out;

    // ws (4B units): H0h [N*16] | q [M] | qp [M] | meta [4*M] | wrowbuf [64]
    //   | gcur [RB] | binned [RB*CAP] | HscA [(M+1)*8] | HscB [(M+1)*8] |
    //   fixedsrc [M*FIX]  -> ~95 MB (all 16B-aligned)
    _Float16* H0h = (_Float16*)d_ws;
    float* q      = (float*)d_ws + (size_t)N * HID / 2;
    float* qp     = q + M;
    int4*  meta   = (int4*)(qp + M);
    float* wrowbuf = (float*)(meta + M);
    int*   gcur   = (int*)(wrowbuf + 64);
    int*   binned = gcur + RB;
    _Float16* HscA = (_Float16*)(binned + (size_t)RB * CAP);
    _Float16* HscB = HscA + (size_t)(M + 1) * 16;
    int* fixedsrc = (int*)(HscB + (size_t)(M + 1) * 16);

    k_gemm_h0<<<(N + GNB - 1) / GNB, BS, 0, stream>>>(x, W1, H0h);
    k_wrow  <<<1, 64, 0, stream>>>(W2, b2, wrowbuf, HscA, HscB);
    hipMemsetAsync(gcur, 0, (size_t)RB * sizeof(int), stream);
    k_scat2 <<<R * NBKr, BS, 0, stream>>>(eis, gcur, binned);
    k_sort3 <<<RB, BSPAN, 0, stream>>>(gcur, binned, meta, (const half8*)H0h,
                                       (half8*)HscA, (half8*)HscB, fixedsrc);
    k_l1<0> <<<(M * 16 + BS - 1) / BS, BS, 0, stream>>>(meta, binned, fixedsrc,
                                                        (const half4*)HscA, b1,
                                                        wrowbuf, qp, q);
    k_l1<1> <<<(M * 16 + BS - 1) / BS, BS, 0, stream>>>(meta, binned, fixedsrc,
                                                        (const half4*)HscB, b1,
                                                        wrowbuf, qp, q);
    k_l2    <<<(M * 8 + BS - 1) / BS, BS, 0, stream>>>(meta, binned, fixedsrc,
                                                       q, wrowbuf, out);
}

// Round 14
// 306.067 us; speedup vs baseline: 1.0965x; 1.0965x over previous
//
#include <hip/hip_runtime.h>

// EdgeFeatGAE: 2-layer GCN (R=4 relations share x, W1, W2), out = sum over
// embed dim -> [R, N].
// Algebra: layer2 collapses to scalar per node (wrow[j] = sum_k W2[j][k]);
// H0 = x@W1 is relation-independent; q[i] = dinv_i * g_i makes layer2 a pure
// scalar gather: out_i = dinv_i*(sum_src q[src] + q[i]) + sum(b2).
// R5-R9: radix-partition + per-bucket counting sort + packed gathers:
// 1738->436us. R11: 16 lanes/node. R12: pre-scaled Hsc=dinv*H0. R13:
// fixedsrc first-16 prefix. R14: register-batched scat2. 406->371us.
// R15: gemm_h0 wave-uniform W1 s_load + LDS-staged x. 371->335us.
// R18 FAILED: per-edge direct scatter -> 64B partial-line writebacks.
// R19: prefix/overflow split (only ~9% of records materialized). ->306.7us.
// R20: meta int4 pack. 306.7us, k_l1 68.0us / FETCH 207MB.
// R21 FAILED (315.7): raw-H0h gather didn't shrink the set (each relation
// already touches only its own 6.4MB Hsc slice) and re-added the dinv
// gather (+14us, matching R12's removal).
// R22 REFUTED the split economics (335.6): j-split HscA/HscB DID cut
// per-pass FETCH 207->72.8MB (L2-fit mechanism confirmed) but per-pass
// time only fell to 53.5us x2 = 107 > 68: each pass is bound by its
// duplicated index-side streams (fixedsrc 25.6MB + meta 6.4MB) + residual
// gather latency. 8-lane variant analyzed: floor ~95us. No split wins.
// R23: REVERT to R20 (best verified, 306.7us). k_l1 sits at the measured
// random-64B-gather equilibrium (3.0 TB/s on 207MB, 58% L2 hit for a
// 6.4MB/relation set); set-size levers probed both ways (R21/R22); the
// mid-pipeline was null-responsive to 3 targeted probes (R16/R20b/R20c).

constexpr int N    = 100000;
constexpr int E    = 1600000;
constexpr int R    = 4;
constexpr int FEAT = 128;
constexpr int HID  = 32;
constexpr int EMB  = 16;
constexpr int M    = R * N;
constexpr int BS   = 256;
constexpr int SH    = 9;                          // bucket = node >> 9
constexpr int BSPAN = 1 << SH;                    // 512 nodes per bucket
constexpr int NBUCK = (N + BSPAN - 1) / BSPAN;    // 196 buckets per relation
constexpr int CH    = 4096;                       // edges per block chunk
constexpr int EPT   = CH / BS;                    // 16 edges per thread
constexpr int NBKr  = (E + CH - 1) / CH;          // 391 blocks per relation
constexpr int RB    = R * NBUCK;                  // 784 buckets total
constexpr int CAP   = 8960;                       // bucket capacity (8.5 sigma)
constexpr int SPT   = (CAP + BSPAN - 1) / BSPAN;  // 18 records per sort thread
constexpr int OCAP  = 1536;                       // overflow cap/bucket (~13 sigma)
constexpr int FIX   = 16;                         // fixed adjacency prefix
constexpr int GNB   = 64;                         // nodes per gemm block (R15)
constexpr int XPITCH = 132;                       // LDS row pitch floats (R15)

typedef _Float16 half8 __attribute__((ext_vector_type(8)));   // 16B chunk
typedef _Float16 half2v __attribute__((ext_vector_type(2)));  // packed pair

// ---------------- H0 = x @ W1  [N,32] -> fp16 ----------------
// R15: lane=node, wave=j-octet (uniform -> W1 via s_load). x staged in LDS
// with XOR-swizzled float4 columns -> conflict-free ds_read_b128.
__global__ __launch_bounds__(BS)
void k_gemm_h0(const float* __restrict__ x, const float* __restrict__ W1,
               _Float16* __restrict__ H0h) {
    __shared__ float xs[GNB * XPITCH];            // 33 KB
    int base = blockIdx.x * GNB;
    int tid  = threadIdx.x;
#pragma unroll
    for (int u = 0; u < 8; ++u) {
        int f = tid + u * BS;          // float4 index in [64][32]
        int n = f >> 5;                // node in block
        int c = f & 31;                // logical float4 column
        if (base + n < N) {
            float4 v = ((const float4*)(x + (size_t)(base + n) * FEAT))[c];
            int p = c ^ ((n & 7) << 2);            // swizzled column
            *(float4*)&xs[n * XPITCH + p * 4] = v;
        }
    }
    __syncthreads();
    int oct = __builtin_amdgcn_readfirstlane(tid >> 6);   // wave-uniform octet
    int l   = tid & 63;                // node owned by this lane
    int i   = base + l;
    const float* wp = W1 + oct * 8;    // uniform base: W1[k][oct*8+j]
    float acc[8];
#pragma unroll
    for (int kk = 0; kk < 8; ++kk) acc[kk] = 0.f;
#pragma unroll 4
    for (int c = 0; c < 32; ++c) {
        int p = c ^ ((l & 7) << 2);
        float4 xv = *(const float4*)&xs[l * XPITCH + p * 4];
        float xk[4] = {xv.x, xv.y, xv.z, xv.w};
#pragma unroll
        for (int dk = 0; dk < 4; ++dk) {
            const float* wr = wp + (c * 4 + dk) * HID;    // uniform -> s_load
#pragma unroll
            for (int j = 0; j < 8; ++j)
                acc[j] = fmaf(xk[dk], wr[j], acc[j]);
        }
    }
    half8 hv;
#pragma unroll
    for (int kk = 0; kk < 8; ++kk) hv[kk] = (_Float16)acc[kk];
    if (i < N) ((half8*)H0h)[i * 4 + oct] = hv;   // 16B store
}

// -------- wrow[j] = sum_k W2[j][k]; wrowbuf[32] = sum(b2); Hsc zero row ----
__global__ void k_wrow(const float* __restrict__ W2, const float* __restrict__ b2,
                       float* __restrict__ wrowbuf, _Float16* __restrict__ Hsc) {
    int j = threadIdx.x;
    if (j < HID) {
        float s = 0.f;
#pragma unroll
        for (int k = 0; k < EMB; ++k) s += W2[j * EMB + k];
        wrowbuf[j] = s;
    } else if (j == HID) {
        float s = 0.f;
#pragma unroll
        for (int k = 0; k < EMB; ++k) s += b2[k];
        wrowbuf[HID] = s;
    } else if (j >= 34 && j < 50) {
        // Hsc zero row (pad-slot target)
        ((unsigned*)(Hsc + (size_t)M * HID))[j - 34] = 0u;
    }
}

// ---------------- partition: register-batched loads (R14) ------------------
__global__ void k_scat2(const int* __restrict__ eis, int* __restrict__ gcur,
                        int* __restrict__ binned) {
    __shared__ int hist[NBUCK], lstart[NBUCK], cursor[NBUCK], gbase[NBUCK];
    __shared__ int wpart[BS / 64];
    __shared__ int shuf[CH];              // 16 KB
    __shared__ unsigned char bkt[CH];     // 4 KB
    int r = blockIdx.x / NBKr, k = blockIdx.x - r * NBKr;
    const int* srcp = eis + (size_t)r * 2 * E;
    const int* dstp = srcp + E;
    int e0 = k * CH, n = min(CH, E - e0);
    int tid = threadIdx.x;

    // R14: batch all global loads up-front into registers.
    int dreg[EPT], sreg[EPT];
    if (n == CH) {
#pragma unroll
        for (int u = 0; u < EPT; ++u) {
            dreg[u] = dstp[e0 + tid + u * BS];
            sreg[u] = srcp[e0 + tid + u * BS];
        }
    } else {
#pragma unroll
        for (int u = 0; u < EPT; ++u) {
            int i = tid + u * BS;
            dreg[u] = (i < n) ? dstp[e0 + i] : -1;   // sentinel
            sreg[u] = (i < n) ? srcp[e0 + i] : 0;
        }
    }
    for (int b = tid; b < NBUCK; b += BS) hist[b] = 0;
    __syncthreads();
#pragma unroll
    for (int u = 0; u < EPT; ++u)
        if (dreg[u] >= 0) atomicAdd(&hist[dreg[u] >> SH], 1);
    __syncthreads();
    // exclusive prefix over NBUCK entries: wave shfl scan (R12)
    int v = (tid < NBUCK) ? hist[tid] : 0;
    int lanei = tid & 63;
    int s = v;
#pragma unroll
    for (int d = 1; d < 64; d <<= 1) {
        int xup = __shfl_up(s, d, 64);
        s += (lanei >= d) ? xup : 0;
    }
    if (lanei == 63) wpart[tid >> 6] = s;
    __syncthreads();
    int offw = 0;
#pragma unroll
    for (int ww = 0; ww < BS / 64; ++ww)
        offw += (ww < (tid >> 6)) ? wpart[ww] : 0;
    int ex = offw + s - v;                // exclusive prefix
    if (tid < NBUCK) {
        lstart[tid] = ex;
        cursor[tid] = ex;
        gbase[tid] = atomicAdd(&gcur[r * NBUCK + tid], v);
    }
    __syncthreads();
    // local scatter into LDS (bucket-ordered), from registers
#pragma unroll
    for (int u = 0; u < EPT; ++u) {
        int d = dreg[u];
        if (d >= 0) {
            int b = d >> SH;
            int pos = atomicAdd(&cursor[b], 1);
            shuf[pos] = ((d & (BSPAN - 1)) << 17) | sreg[u];   // src < 2^17
            bkt[pos]  = (unsigned char)b;
        }
    }
    __syncthreads();
    // coalesced emission into CAP-strided bucket segments (R20 unroll)
    if (n == CH) {
#pragma unroll
        for (int u = 0; u < EPT; ++u) {
            int i = tid + u * BS;
            int b = bkt[i];
            int pos = gbase[b] + (i - lstart[b]);
            if (pos < CAP)
                binned[(size_t)(r * NBUCK + b) * CAP + pos] = shuf[i];
        }
    } else {
        for (int i = tid; i < n; i += BS) {
            int b = bkt[i];
            int pos = gbase[b] + (i - lstart[b]);
            if (pos < CAP)
                binned[(size_t)(r * NBUCK + b) * CAP + pos] = shuf[i];
        }
    }
}

// ------ per-bucket prefix/overflow split (R19) + meta + fused epilogue -----
// Counts per node, writes fixed-16 prefix via fix_lds (coalesced), and the
// ~9% overflow compactly into the TAIL of this bucket's binned segment.
__global__ __launch_bounds__(BSPAN)
void k_sort3(const int* __restrict__ gcur, int* __restrict__ binned,
             int4* __restrict__ meta, const half8* __restrict__ H0h,
             half8* __restrict__ Hsc, int* __restrict__ fixedsrc) {
    __shared__ int fix_lds[FIX * BSPAN];            // 32 KB, transposed [k][node]
    __shared__ int hist[BSPAN], cur[BSPAN], oexs[BSPAN];  // 6 KB
    __shared__ int wpart[BSPAN / 64];
    int gb = blockIdx.x;
    int r = gb / NBUCK, b = gb - r * NBUCK;
    int n = min(gcur[gb], CAP);
    int base = gb * CAP;
    int ovb  = base + (CAP - OCAP);       // overflow region: tail of own segment
    int tid = threadIdx.x;                // 0..511
    int node = (b << SH) + tid;
    int ri = r * N + node;
    // R20: H0h self-row loads have static addresses - issue at entry.
    int nodec = min(node, N - 1);
    half8 h0r[4];
#pragma unroll
    for (int cc = 0; cc < 4; ++cc) h0r[cc] = H0h[(size_t)nodec * 4 + cc];
    // register-resident records (R16): all loads in flight, no LDS staging
    int rg[SPT];
#pragma unroll
    for (int u = 0; u < SPT; ++u) {
        int i = tid + u * BSPAN;
        rg[u] = (i < n) ? binned[base + i] : -1;    // values >= 0; -1 sentinel
    }
    hist[tid] = 0;
    cur[tid] = 0;
    __syncthreads();
#pragma unroll
    for (int u = 0; u < SPT; ++u)
        if (rg[u] >= 0) atomicAdd(&hist[((unsigned)rg[u]) >> 17], 1);
    __syncthreads();
    int v = hist[tid];
    int ov = max(v - FIX, 0);             // this node's overflow count
    // wave shfl scan + cross-wave pass over overflow counts
    int lanei = tid & 63;
    int s = ov;
#pragma unroll
    for (int d = 1; d < 64; d <<= 1) {
        int xup = __shfl_up(s, d, 64);
        s += (lanei >= d) ? xup : 0;
    }
    if (lanei == 63) wpart[tid >> 6] = s;
    __syncthreads();
    int offw = 0;
#pragma unroll
    for (int ww = 0; ww < BSPAN / 64; ++ww)
        offw += (ww < (tid >> 6)) ? wpart[ww] : 0;
    int oex = offw + s - ov;              // exclusive prefix of overflow
    oexs[tid] = oex;
    float di = rsqrtf((float)v + 1.0f);
    if (node < N) {
        int4 mw;
        mw.x = min(v, FIX + max(OCAP - oex, 0));   // clamped cnt (13-sigma no-op)
        mw.y = ovb + oex;                          // overflow base
        mw.z = __float_as_int(di);                 // dinv bits
        mw.w = 0;
        meta[ri] = mw;                             // one coalesced 16B store
    }
    __syncthreads();
    // split scatter: k<FIX -> fix_lds (coalesced out later); else -> compact
    // overflow tail. Arrival order arbitrary = correct (commutative sum,
    // validated R18). Reads of rg are register-resident -> tail aliasing ok.
#pragma unroll
    for (int u = 0; u < SPT; ++u) {
        int rc = rg[u];
        if (rc >= 0) {
            int nd = ((unsigned)rc) >> 17;
            int k = atomicAdd(&cur[nd], 1);
            int val = rc & 0x1FFFF;
            if (k < FIX) {
                fix_lds[k * BSPAN + nd] = val;
            } else {
                int p = oexs[nd] + k - FIX;
                if (p < OCAP) binned[ovb + p] = val;
            }
        }
    }
    __syncthreads();
    // fused epilogue: fixedsrc prefix + Hsc = dinv*H0 (fp16), all coalesced
    if (node < N) {
        int nn = min(v, FIX);
#pragma unroll
        for (int cc = 0; cc < 4; ++cc) {
            int4 w;
            w.x = (cc * 4 + 0 < nn) ? fix_lds[(cc * 4 + 0) * BSPAN + tid] : 0;
            w.y = (cc * 4 + 1 < nn) ? fix_lds[(cc * 4 + 1) * BSPAN + tid] : 0;
            w.z = (cc * 4 + 2 < nn) ? fix_lds[(cc * 4 + 2) * BSPAN + tid] : 0;
            w.w = (cc * 4 + 3 < nn) ? fix_lds[(cc * 4 + 3) * BSPAN + tid] : 0;
            ((int4*)(fixedsrc + (size_t)ri * FIX))[cc] = w;   // coalesced 64B
        }
#pragma unroll
        for (int cc = 0; cc < 4; ++cc) {
            half8 h = h0r[cc];
            half8 o;
#pragma unroll
            for (int kk = 0; kk < 8; ++kk) o[kk] = (_Float16)(di * (float)h[kk]);
            Hsc[(size_t)ri * 4 + cc] = o;                     // coalesced 64B
        }
    }
}

// ---------------- layer 1: 16 lanes/node, 4 lanes/record, pure add-gather --
// Window 0 from fixedsrc (static addr, 2-hop chain). Windows >=16 map onto
// the compact overflow list via base = ovoff - FIX. Window 1 prefetched.
// R20: one int4 meta load replaces cnt/ovoff/dinv; self-row hoisted to entry.
__global__ void k_l1(const int4* __restrict__ meta, const int* __restrict__ ssrc,
                     const int* __restrict__ fixedsrc, const half8* __restrict__ Hsc,
                     const float* __restrict__ b1, const float* __restrict__ wrowbuf,
                     float* __restrict__ q) {
    int t = blockIdx.x * blockDim.x + threadIdx.x;
    int ri = t >> 4;
    if (ri >= M) return;
    int lane = t & 15;
    int c   = lane & 3;        // 16B chunk of the 64B row
    int sub = lane >> 2;       // record slot 0..3
    int i = ri % N;
    int rbase = ri - i;
    int fs = fixedsrc[(size_t)ri * FIX + lane];    // STATIC addr: issues now
    half8 hs = Hsc[(size_t)ri * 4 + c];            // STATIC addr: self row
    int4 mo = meta[ri];                            // one dwordx4: cnt|ovoff|dinv
    int n = mo.x;
    int base = mo.y - FIX;                         // virtual base for k0>=16
    float di = __int_as_float(mo.z);
    half2v acc[4];
    half2v zz = {(_Float16)0.f, (_Float16)0.f};
#pragma unroll
    for (int kk = 0; kk < 4; ++kk) acc[kk] = zz;

    auto procwin = [&](int sbv, int m) {
        for (int bq = 0; bq < 4 && bq * 4 < m; ++bq) {
            int slot = bq * 4 + sub;
            int sj = __shfl(sbv, slot, 16);
            int idx = (slot < m) ? (rbase + sj) : M;   // zero row for pad slots
            half8 h = Hsc[(size_t)idx * 4 + c];
#pragma unroll
            for (int kk = 0; kk < 4; ++kk) {
                half2v hp = {h[2 * kk], h[2 * kk + 1]};
                acc[kk] = acc[kk] + hp;         // v_pk_add_f16
            }
        }
    };

    // prefetch window 1 (first overflow window) before processing window 0
    int sb = (16 + lane < n) ? ssrc[base + 16 + lane] : 0;
    procwin(fs, n);                                 // window 0 (from fixed)
    for (int k0 = 16; k0 < n; k0 += 16) {
        int sbn = (k0 + 16 + lane < n) ? ssrc[base + k0 + 16 + lane] : 0;
        procwin(sb, n - k0);
        sb = sbn;
    }
    // packed reduction over record slots (lanes c, c+4, c+8, c+12 same chunk)
#pragma unroll
    for (int o = 4; o <= 8; o <<= 1) {
#pragma unroll
        for (int kk = 0; kk < 4; ++kk) {
            int av = __builtin_bit_cast(int, acc[kk]);
            av = __shfl_xor(av, o, 16);
            acc[kk] = acc[kk] + __builtin_bit_cast(half2v, av);  // v_pk_add_f16
        }
    }
    // self term: + Hsc[ri]  (h1 = di*(sum_src + self) + b1)
#pragma unroll
    for (int kk = 0; kk < 4; ++kk) {
        half2v hp = {hs[2 * kk], hs[2 * kk + 1]};
        acc[kk] = acc[kk] + hp;
    }
    // epilogue: h1 = relu(di*acc + b1); p = h1 . wrow
    float p = 0.f;
#pragma unroll
    for (int kk = 0; kk < 8; ++kk) {
        float av = (float)acc[kk >> 1][kk & 1];
        int j = c * 8 + kk;
        float h1 = fmaf(di, av, b1[j]);
        h1 = fmaxf(h1, 0.f);
        p = fmaf(h1, wrowbuf[j], p);
    }
    p += __shfl_xor(p, 1, 16);
    p += __shfl_xor(p, 2, 16);
    if (lane == 0) q[ri] = di * p;              // q = dinv * g
}

// ---------------- layer 2: per-lane scalar gathers of q + finalize ----------
__global__ void k_l2(const int4* __restrict__ meta, const int* __restrict__ ssrc,
                     const int* __restrict__ fixedsrc, const float* __restrict__ q,
                     const float* __restrict__ wrowbuf, float* __restrict__ out) {
    int t = blockIdx.x * blockDim.x + threadIdx.x;
    int ri = t >> 3;
    if (ri >= M) return;
    int lane = t & 7;
    int i = ri % N;
    int rbase = ri - i;
    int f0 = fixedsrc[(size_t)ri * FIX + lane];        // static addr
    int f1 = fixedsrc[(size_t)ri * FIX + 8 + lane];    // static addr
    int4 mo = meta[ri];                                // cnt | ovoff | dinv
    int n = mo.x;
    int base = mo.y - FIX;
    float val = 0.f;
    if (lane < n)     val += q[rbase + f0];
    if (8 + lane < n) val += q[rbase + f1];
    for (int idx = 16 + lane; idx < n; idx += 8) {
        int s = ssrc[base + idx];               // coalesced (overflow list)
        val += q[rbase + s];                    // 4B gather, 1.6MB L2-resident
    }
#pragma unroll
    for (int o = 4; o > 0; o >>= 1) val += __shfl_xor(val, o, 8);
    if (lane == 0)
        out[ri] = __int_as_float(mo.z) * (val + q[ri]) + wrowbuf[HID];
}

extern "C" void kernel_launch(void* const* d_in, const int* in_sizes, int n_in,
                              void* d_out, int out_size, void* d_ws, size_t ws_size,
                              hipStream_t stream) {
    const float* x  = (const float*)d_in[0];
    const int*  eis = (const int*)d_in[1];
    const float* W1 = (const float*)d_in[2];
    const float* b1 = (const float*)d_in[3];
    const float* W2 = (const float*)d_in[4];
    const float* b2 = (const float*)d_in[5];
    float* out = (float*)d_out;

    // ws (4B units): H0h [N*16] | q [M] | meta [4*M] | wrowbuf [64] |
    //   gcur [RB] | binned [RB*CAP] | Hsc [(M+1)*16] | fixedsrc [M*FIX]
    //   -> ~92 MB (overflow list lives inside binned tail)
    _Float16* H0h = (_Float16*)d_ws;
    float* q      = (float*)d_ws + (size_t)N * HID / 2;
    int4*  meta   = (int4*)(q + M);
    float* wrowbuf = (float*)(meta + M);
    int*   gcur   = (int*)(wrowbuf + 64);
    int*   binned = gcur + RB;
    _Float16* Hsc = (_Float16*)(binned + (size_t)RB * CAP);
    int* fixedsrc = (int*)(Hsc + (size_t)(M + 1) * HID);

    k_gemm_h0<<<(N + GNB - 1) / GNB, BS, 0, stream>>>(x, W1, H0h);
    k_wrow  <<<1, 64, 0, stream>>>(W2, b2, wrowbuf, Hsc);
    hipMemsetAsync(gcur, 0, (size_t)RB * sizeof(int), stream);
    k_scat2 <<<R * NBKr, BS, 0, stream>>>(eis, gcur, binned);
    k_sort3 <<<RB, BSPAN, 0, stream>>>(gcur, binned, meta,
                                       (const half8*)H0h, (half8*)Hsc, fixedsrc);
    k_l1    <<<(M * 16 + BS - 1) / BS, BS, 0, stream>>>(meta, binned, fixedsrc,
                                                        (const half8*)Hsc, b1,
                                                        wrowbuf, q);
    k_l2    <<<(M * 8 + BS - 1) / BS, BS, 0, stream>>>(meta, binned, fixedsrc,
                                                       q, wrowbuf, out);
}